// Round 1
// baseline (168.521 us; speedup 1.0000x reference)
//
#include <hip/hip_runtime.h>

// h_t = a*h_{t-1} + b*x_t + c, h_{-1}=0; z = w*h_{T-1} + e
//
// Closed form: h_{T-1} = b * sum_t a^{T-1-t} x_t  +  c * (1-a^T)/(1-a).
// With a <= 0.999 (setup guarantees [0.95, 0.999]), weights a^o underflow
// fp64 by o ~ 745/|ln a| <= 745k, and drop below any fp32-visible
// contribution by o ~ 35k. TAIL_K = 131072 leaves ~1e-54 relative residue.
// So we read only the last 512 KB of the 128 MB input.

#define TAIL_K   131072
#define NBLOCKS  64
#define BLOCK    256

__global__ __launch_bounds__(BLOCK) void tail_weighted_sum(
    const float* __restrict__ x,
    const float* __restrict__ a_p,
    long long T, int K,
    double* __restrict__ partials)
{
    const double a  = (double)a_p[0];
    const int    NT = gridDim.x * blockDim.x;          // 16384 threads
    const int    g  = blockIdx.x * blockDim.x + threadIdx.x;

    // weight for offset-from-end o is a^o; this thread handles o = g, g+NT, ...
    double wgt        = pow(a, (double)g);
    const double mult = pow(a, (double)NT);
    double acc = 0.0;

    for (long long o = g; o < (long long)K; o += NT) {
        const long long idx = T - 1 - o;               // coalesced (reversed)
        acc += wgt * (double)x[idx];
        wgt *= mult;
        if (wgt == 0.0) break;                         // fp64 underflow: done
    }

    __shared__ double sdata[BLOCK];
    sdata[threadIdx.x] = acc;
    __syncthreads();
    #pragma unroll
    for (int off = BLOCK / 2; off > 0; off >>= 1) {
        if (threadIdx.x < off) sdata[threadIdx.x] += sdata[threadIdx.x + off];
        __syncthreads();
    }
    if (threadIdx.x == 0) partials[blockIdx.x] = sdata[0];
}

__global__ void finalize(
    const double* __restrict__ partials, int nparts,
    const float* __restrict__ a_p, const float* __restrict__ b_p,
    const float* __restrict__ c_p, const float* __restrict__ w_p,
    const float* __restrict__ e_p,
    long long T, float* __restrict__ out)
{
    const int lane = threadIdx.x;                      // one wave of 64
    double s = (lane < nparts) ? partials[lane] : 0.0;
    #pragma unroll
    for (int off = 32; off > 0; off >>= 1)
        s += __shfl_down(s, off, 64);

    if (lane == 0) {
        const double a = (double)a_p[0];
        const double b = (double)b_p[0];
        const double c = (double)c_p[0];
        const double w = (double)w_p[0];
        const double e = (double)e_p[0];
        const double aT = pow(a, (double)T);           // ~0 (fp64 underflow)
        const double G  = (1.0 - aT) / (1.0 - a);      // sum_{k=0}^{T-1} a^k
        const double h  = b * s + c * G;
        out[0] = (float)(w * h + e);
    }
}

extern "C" void kernel_launch(void* const* d_in, const int* in_sizes, int n_in,
                              void* d_out, int out_size, void* d_ws, size_t ws_size,
                              hipStream_t stream)
{
    const float* x = (const float*)d_in[0];
    const float* a = (const float*)d_in[1];
    const float* b = (const float*)d_in[2];
    const float* c = (const float*)d_in[3];
    const float* w = (const float*)d_in[4];
    const float* e = (const float*)d_in[5];
    float* out = (float*)d_out;

    const long long T = (long long)in_sizes[0];
    int K = TAIL_K;
    if ((long long)K > T) K = (int)T;

    double* partials = (double*)d_ws;                  // 64 * 8 B = 512 B

    tail_weighted_sum<<<NBLOCKS, BLOCK, 0, stream>>>(x, a, T, K, partials);
    finalize<<<1, 64, 0, stream>>>(partials, NBLOCKS, a, b, c, w, e, T, out);
}